// Round 19
// baseline (217.051 us; speedup 1.0000x reference)
//
#include <hip/hip_runtime.h>
#include <stdint.h>

// Problem constants
#define BB 8
#define NN 1024
#define DDIM 768
#define HH 12
#define HDIM 64
#define D3 2304   // 3*D
#define MM 8192   // B*N

typedef __attribute__((ext_vector_type(4))) float f32x4;
typedef __attribute__((ext_vector_type(16))) float f32x16;
typedef __attribute__((ext_vector_type(8))) __bf16 bf16x8;
typedef __attribute__((ext_vector_type(8))) unsigned short u16x8;
typedef __attribute__((ext_vector_type(4))) unsigned short u16x4;

__device__ __forceinline__ unsigned short f2bf(float f) {
  unsigned int u = __float_as_uint(f);
  u += 0x7FFFu + ((u >> 16) & 1u);   // RNE
  return (unsigned short)(u >> 16);
}

__device__ __forceinline__ void gload_lds16(const void* g, void* l) {
  __builtin_amdgcn_global_load_lds((const __attribute__((address_space(1))) void*)g,
                                   (__attribute__((address_space(3))) void*)l,
                                   16, 0, 0);
}

__device__ __forceinline__ unsigned cvtpk_bf16(float lo, float hi) {
  unsigned r;
  asm("v_cvt_pk_bf16_f32 %0, %1, %2" : "=v"(r) : "v"(lo), "v"(hi));
  return r;
}

__device__ __forceinline__ bf16x8 mkfrag(unsigned a, unsigned b, unsigned c, unsigned d) {
  union { unsigned u[4]; bf16x8 v; } x;
  x.u[0] = a; x.u[1] = b; x.u[2] = c; x.u[3] = d;
  return x.v;
}

#if __has_builtin(__builtin_amdgcn_exp2f)
#define EXP2(x) __builtin_amdgcn_exp2f(x)
#else
#define EXP2(x) exp2f(x)
#endif

// scale folded into Q at GEMM epilogue: 1/sqrt(64) * log2(e)
#define QSCL 0.18033688f

// ---------------- Kernel 1: merged prep: x fp32->bf16 + W transpose ----------------
__global__ void k_prep(const float4* __restrict__ x, u16x4* __restrict__ xb,
                       const float* __restrict__ W, unsigned short* __restrict__ Wt) {
  __shared__ float tile[32][33];
  const int bid = blockIdx.x;
  if (bid < 6144) {
    int i = bid * 256 + threadIdx.x;
    float4 v = x[i];
    u16x4 o;
    o[0] = f2bf(v.x); o[1] = f2bf(v.y); o[2] = f2bf(v.z); o[3] = f2bf(v.w);
    xb[i] = o;
    return;
  }
  const int bid2 = bid - 6144;
  const int tx = threadIdx.x & 31, ty = threadIdx.x >> 5;
  const int n0 = (bid2 % 72) * 32;
  const int k0 = (bid2 / 72) * 32;
  for (int i = 0; i < 4; ++i) {
    int k = k0 + ty + i * 8;
    tile[ty + i * 8][tx] = W[(size_t)k * D3 + n0 + tx];
  }
  __syncthreads();
  for (int i = 0; i < 4; ++i) {
    int n = n0 + ty + i * 8;
    Wt[(size_t)n * DDIM + k0 + tx] = f2bf(tile[tx][ty + i * 8]);
  }
}

// ---------------- Kernel 2: QKV GEMM (m97 structure) + fused pack epilogue ----------
// 128x128 tile, BK=64, 2-buffer 64KB, XOR-swizzled rows, stage-at-top + vmcnt(8),
// 2 barriers/kt — the R12-proven core (745 TF here) — with m-stripe XCD swizzle.
// Epilogue: nt 0-5 -> compact Q [8192][768]*QSCL; 6-11 -> K pack; 12-17 -> V^T pack.
__global__ __launch_bounds__(256, 2)
void k_gemm(const unsigned short* __restrict__ A, const unsigned short* __restrict__ Bt,
            const float* __restrict__ bias, unsigned short* __restrict__ qb,
            unsigned short* __restrict__ kp, unsigned short* __restrict__ vp) {
  __shared__ char lds[64 * 1024];   // 2 bufs x (A 16KB + B 16KB)
  const int t = threadIdx.x, lane = t & 63, wid = t >> 6;
  // m-stripe XCD swizzle: xcd owns m-tiles [xcd*8, xcd*8+8), n-major inner
  const int orig = blockIdx.x;          // 1152 = 8 xcd * 144
  const int xcd = orig & 7, tt = orig >> 3;
  const int m0 = (xcd * 8 + (tt & 7)) * 128;
  const int n0 = (tt >> 3) * 128;
  const int wr = wid >> 1, wc = wid & 1;
  const int grp = lane >> 4, lc = lane & 15;

  f32x4 acc[4][4];
  for (int i = 0; i < 4; ++i)
    for (int j = 0; j < 4; ++j) acc[i][j] = (f32x4)(0.0f);

  // stage one BK=64 tile pair: A[128][64], B[128][64], XOR-swizzled rows; 8 issues/wave
  auto STAGE = [&](int buf, int kt) {
    char* Ab = lds + buf * 32768;
    char* Bb = Ab + 16384;
#pragma unroll
    for (int i = 0; i < 4; ++i) {
      int id = wid * 4 + i;              // chunk 0..15 (8 rows each)
      int row = id * 8 + (lane >> 3);
      int cs = ((lane & 7) << 4) ^ ((row & 7) << 4);
      gload_lds16((const char*)A + (size_t)(m0 + row) * 1536 + kt * 128 + cs, Ab + id * 1024);
      gload_lds16((const char*)Bt + (size_t)(n0 + row) * 1536 + kt * 128 + cs, Bb + id * 1024);
    }
  };

  STAGE(0, 0);
  for (int kt = 0; kt < 12; ++kt) {
    if (kt < 11) {
      STAGE((kt + 1) & 1, kt + 1);                      // prefetch stays in flight
      asm volatile("s_waitcnt vmcnt(8)" ::: "memory");  // drain only buf(kt)
    } else {
      asm volatile("s_waitcnt vmcnt(0)" ::: "memory");
    }
    __builtin_amdgcn_s_barrier();

    const char* As = lds + (kt & 1) * 32768;
    const char* Bs = As + 16384;
    bf16x8 af[4][2], bfr[4][2];
#pragma unroll
    for (int f = 0; f < 4; ++f)
#pragma unroll
      for (int kk = 0; kk < 2; ++kk) {
        int ra = wr * 64 + f * 16 + lc;
        af[f][kk] = *(const bf16x8*)(As + ra * 128 + ((kk * 64 + grp * 16) ^ ((ra & 7) << 4)));
        int rb = wc * 64 + f * 16 + lc;
        bfr[f][kk] = *(const bf16x8*)(Bs + rb * 128 + ((kk * 64 + grp * 16) ^ ((rb & 7) << 4)));
      }
    __builtin_amdgcn_s_setprio(1);
#pragma unroll
    for (int mf = 0; mf < 4; ++mf)
#pragma unroll
      for (int nf = 0; nf < 4; ++nf) {
        acc[mf][nf] = __builtin_amdgcn_mfma_f32_16x16x32_bf16(af[mf][0], bfr[nf][0], acc[mf][nf], 0, 0, 0);
        acc[mf][nf] = __builtin_amdgcn_mfma_f32_16x16x32_bf16(af[mf][1], bfr[nf][1], acc[mf][nf], 0, 0, 0);
      }
    __builtin_amdgcn_s_setprio(0);
    __builtin_amdgcn_s_barrier();                       // buf(kt) free for restage
  }

  float bv[4];
#pragma unroll
  for (int nf = 0; nf < 4; ++nf) bv[nf] = bias[n0 + wc * 64 + nf * 16 + lc];

  const int nt = n0 >> 7;   // 0..17: Q<6, K<12, else V
  if (nt < 6) {
    // Q: compact [8192][768] bf16, pre-scaled by QSCL
#pragma unroll
    for (int mf = 0; mf < 4; ++mf)
#pragma unroll
      for (int nf = 0; nf < 4; ++nf)
#pragma unroll
        for (int i = 0; i < 4; ++i) {
          int r = m0 + wr * 64 + mf * 16 + grp * 4 + i;
          int c = n0 + wc * 64 + nf * 16 + lc;
          qb[(size_t)r * DDIM + c] = f2bf((acc[mf][nf][i] + bv[nf]) * QSCL);
        }
  } else {
    __syncthreads();   // main-loop LDS reads done in all waves before reuse
    unsigned short* lt = (unsigned short*)lds + wid * 4608;   // 64 x 72 per wave
    const int l31 = lane & 31, hi2 = lane >> 5;
    const int bb = m0 >> 10;
    const int kt_ = ((m0 & 1023) >> 6) + wr;   // 64-token pack tile
    size_t base;
    unsigned short* dst;
    if (nt < 12) {
      // K: LDS [tok][d]
      const int h = ((n0 - DDIM) >> 6) + wc;
      base = ((size_t)(bb * HH + h) * 16 + kt_) * 4096;
      dst = kp;
#pragma unroll
      for (int mf = 0; mf < 4; ++mf)
#pragma unroll
        for (int nf = 0; nf < 4; ++nf)
#pragma unroll
          for (int i = 0; i < 4; ++i)
            lt[(mf * 16 + grp * 4 + i) * 72 + nf * 16 + lc] = f2bf(acc[mf][nf][i] + bv[nf]);
    } else {
      // V: LDS [d][tok]  (transposed)
      const int h = ((n0 - 2 * DDIM) >> 6) + wc;
      base = ((size_t)(bb * HH + h) * 16 + kt_) * 4096;
      dst = vp;
#pragma unroll
      for (int mf = 0; mf < 4; ++mf)
#pragma unroll
        for (int nf = 0; nf < 4; ++nf)
#pragma unroll
          for (int i = 0; i < 4; ++i)
            lt[(nf * 16 + lc) * 72 + mf * 16 + grp * 4 + i] = f2bf(acc[mf][nf][i] + bv[nf]);
    }
    __syncthreads();   // (also orders each wave's own writes before reads)
    // pack store: chunk c2*2+r, lane holds 8 ushorts at row (r*32+l31), col c2*16+hi2*8
#pragma unroll
    for (int c2 = 0; c2 < 4; ++c2)
#pragma unroll
      for (int r = 0; r < 2; ++r)
        *(u16x8*)(dst + base + ((size_t)(c2 * 2 + r) * 64 + lane) * 8) =
          *(const u16x8*)&lt[(r * 32 + l31) * 72 + c2 * 16 + hi2 * 8];
  }
}

// ---------------- Kernel 3: flash attention (T15 att[2] double-pipeline) ------------
// Tile kt+1's QK^T (pure MFMA on staged K + resident Q) issues BEFORE tile kt's
// softmax/PV — matrix pipe drains while VALU runs exp/cvt of the previous tile.
// K and V in independent 3-deep 8KB rings (48KB total): K read 1 tile ahead of V.
// One barrier/iter; steady vmcnt(4) (K(kt+1),V(kt) proven landed), tail 2 -> 0.
__global__ __launch_bounds__(256, 3)
void k_attn(const unsigned short* __restrict__ qb,
            const unsigned short* __restrict__ kp, const unsigned short* __restrict__ vp,
            float* __restrict__ out) {
  __shared__ char lds[48 * 1024];   // K bufs @ b*8192 (b=0..2); V bufs @ 24576 + b*8192
  const int lane = threadIdx.x & 63, wid = threadIdx.x >> 6;
  const int orig = blockIdx.x;
  const int wg = (orig & 7) * 96 + (orig >> 3);
  const int bh = wg >> 3, qt = wg & 7;
  const int b = bh / HH, h = bh % HH;
  const int q0 = qt * 128 + wid * 32;
  const int l31 = lane & 31, hi = lane >> 5;

  auto STAGE_K = [&](int bi, int kt2) {
    char* buf = lds + bi * 8192;
    const char* gk = (const char*)kp + (size_t)(bh * 16 + kt2) * 8192 + lane * 16;
#pragma unroll
    for (int i = 0; i < 2; ++i) {
      int c = wid * 2 + i;
      gload_lds16(gk + c * 1024, buf + c * 1024);
    }
  };
  auto STAGE_V = [&](int bi, int kt2) {
    char* buf = lds + 24576 + bi * 8192;
    const char* gv = (const char*)vp + (size_t)(bh * 16 + kt2) * 8192 + lane * 16;
#pragma unroll
    for (int i = 0; i < 2; ++i) {
      int c = wid * 2 + i;
      gload_lds16(gv + c * 1024, buf + c * 1024);
    }
  };

  // Q fragments FIRST (their 4 loads drain ahead of K0 in vmcnt FIFO order)
  bf16x8 qf[4];
  const char* qbase = (const char*)qb + ((size_t)(b * NN + q0 + l31) * DDIM + h * HDIM) * 2;
#pragma unroll
  for (int ds_ = 0; ds_ < 4; ++ds_)
    qf[ds_] = *(const bf16x8*)(qbase + ds_ * 32 + hi * 16);

  // prologue stages: K0,V0,K1,V1,K2  (10 loads/wave incl. 4 qf => vmcnt(8) drains qf+K0)
  STAGE_K(0, 0); STAGE_V(0, 0);
  STAGE_K(1, 1); STAGE_V(1, 1);
  STAGE_K(2, 2);

  f32x16 acc0 = (f32x16)(0.0f), acc1 = (f32x16)(0.0f);
  float l = 0.0f;

  f32x16 stA0 = (f32x16)(0.0f), stA1 = (f32x16)(0.0f);
  f32x16 stB0 = (f32x16)(0.0f), stB1 = (f32x16)(0.0f);

  asm volatile("s_waitcnt vmcnt(8)" ::: "memory");   // qf + K(0) landed
  __builtin_amdgcn_s_barrier();
  {
    const char* Kc = lds;   // K buf 0
    __builtin_amdgcn_s_setprio(1);
#pragma unroll
    for (int ds_ = 0; ds_ < 4; ++ds_) {
      bf16x8 k0 = *(const bf16x8*)(Kc + (ds_ * 2 + 0) * 1024 + lane * 16);
      bf16x8 k1 = *(const bf16x8*)(Kc + (ds_ * 2 + 1) * 1024 + lane * 16);
      stA0 = __builtin_amdgcn_mfma_f32_32x32x16_bf16(k0, qf[ds_], stA0, 0, 0, 0);
      stA1 = __builtin_amdgcn_mfma_f32_32x32x16_bf16(k1, qf[ds_], stA1, 0, 0, 0);
    }
    __builtin_amdgcn_s_setprio(0);
  }

#pragma unroll
  for (int kt = 0; kt < 16; ++kt) {
    // steady: in flight = {K(kt+1),V(kt)} (iter kt-2) + {K(kt+2),V(kt+1)} (iter kt-1)
    // vmcnt(4) drains the older pair -> K(kt+1), V(kt) proven in LDS.
    if (kt < 14)       asm volatile("s_waitcnt vmcnt(4)" ::: "memory");
    else if (kt == 14) asm volatile("s_waitcnt vmcnt(2)" ::: "memory");
    else               asm volatile("s_waitcnt vmcnt(0)" ::: "memory");
    __builtin_amdgcn_s_barrier();   // all waves past iter kt-1 reads -> ring slots free
    if (kt + 3 < 16) STAGE_K((kt + 3) % 3, kt + 3);
    if (kt + 2 < 16) STAGE_V((kt + 2) % 3, kt + 2);

    const bool even = (kt & 1) == 0;
    f32x16& sc0 = even ? stA0 : stB0;
    f32x16& sc1 = even ? stA1 : stB1;
    f32x16& sn0 = even ? stB0 : stA0;
    f32x16& sn1 = even ? stB1 : stA1;

    // next tile's QK^T — MFMA pipe; independent of this tile's softmax (VALU)
    if (kt < 15) {
      const char* Kn = lds + ((kt + 1) % 3) * 8192;
      sn0 = (f32x16)(0.0f); sn1 = (f32x16)(0.0f);
      __builtin_amdgcn_s_setprio(1);
#pragma unroll
      for (int ds_ = 0; ds_ < 4; ++ds_) {
        bf16x8 k0 = *(const bf16x8*)(Kn + (ds_ * 2 + 0) * 1024 + lane * 16);
        bf16x8 k1 = *(const bf16x8*)(Kn + (ds_ * 2 + 1) * 1024 + lane * 16);
        sn0 = __builtin_amdgcn_mfma_f32_32x32x16_bf16(k0, qf[ds_], sn0, 0, 0, 0);
        sn1 = __builtin_amdgcn_mfma_f32_32x32x16_bf16(k1, qf[ds_], sn1, 0, 0, 0);
      }
      __builtin_amdgcn_s_setprio(0);
    }

    const char* Vc = lds + 24576 + (kt % 3) * 8192;
    bf16x8 vf[4][2];
#pragma unroll
    for (int cc = 0; cc < 4; ++cc)
#pragma unroll
      for (int r = 0; r < 2; ++r)
        vf[cc][r] = *(const bf16x8*)(Vc + (cc * 2 + r) * 1024 + lane * 16);

    // softmax (constant shift; scale folded into Q) on CURRENT tile
    float s0 = 0.f, s1 = 0.f, s2 = 0.f, s3 = 0.f;
#pragma unroll
    for (int i = 0; i < 16; i += 4) {
      float p0 = EXP2(sc0[i]);
      float p1 = EXP2(sc0[i + 1]);
      float p2 = EXP2(sc0[i + 2]);
      float p3 = EXP2(sc0[i + 3]);
      sc0[i] = p0; sc0[i + 1] = p1; sc0[i + 2] = p2; sc0[i + 3] = p3;
      s0 += p0; s1 += p1; s2 += p2; s3 += p3;
    }
#pragma unroll
    for (int i = 0; i < 16; i += 4) {
      float p0 = EXP2(sc1[i]);
      float p1 = EXP2(sc1[i + 1]);
      float p2 = EXP2(sc1[i + 2]);
      float p3 = EXP2(sc1[i + 3]);
      sc1[i] = p0; sc1[i + 1] = p1; sc1[i + 2] = p2; sc1[i + 3] = p3;
      s0 += p0; s1 += p1; s2 += p2; s3 += p3;
    }
    l += (s0 + s1) + (s2 + s3);

#pragma unroll
    for (int kblk = 0; kblk < 2; ++kblk) {
      const f32x16& sp = kblk ? sc1 : sc0;
      unsigned c0 = cvtpk_bf16(sp[0], sp[1]),   c1 = cvtpk_bf16(sp[2], sp[3]);
      unsigned c2 = cvtpk_bf16(sp[4], sp[5]),   c3 = cvtpk_bf16(sp[6], sp[7]);
      unsigned c4 = cvtpk_bf16(sp[8], sp[9]),   c5 = cvtpk_bf16(sp[10], sp[11]);
      unsigned c6 = cvtpk_bf16(sp[12], sp[13]), c7 = cvtpk_bf16(sp[14], sp[15]);
      unsigned z0 = hi ? c0 : c2, z1 = hi ? c1 : c3;
      unsigned z2 = hi ? c4 : c6, z3 = hi ? c5 : c7;
      unsigned w0 = __shfl_xor(z0, 32, 64), w1 = __shfl_xor(z1, 32, 64);
      unsigned w2 = __shfl_xor(z2, 32, 64), w3 = __shfl_xor(z3, 32, 64);
      bf16x8 pf0 = mkfrag(hi ? w0 : c0, hi ? w1 : c1, hi ? c2 : w0, hi ? c3 : w1);
      bf16x8 pf1 = mkfrag(hi ? w2 : c4, hi ? w3 : c5, hi ? c6 : w2, hi ? c7 : w3);

      __builtin_amdgcn_s_setprio(1);
#pragma unroll
      for (int ch = 0; ch < 2; ++ch) {
        const int cc = kblk * 2 + ch;
        const bf16x8 pf = ch ? pf1 : pf0;
        acc0 = __builtin_amdgcn_mfma_f32_32x32x16_bf16(vf[cc][0], pf, acc0, 0, 0, 0);
        acc1 = __builtin_amdgcn_mfma_f32_32x32x16_bf16(vf[cc][1], pf, acc1, 0, 0, 0);
      }
      __builtin_amdgcn_s_setprio(0);
    }
  }

  float lf = l + __shfl_xor(l, 32, 64);
  float inv = 1.0f / lf;
  float* obase = out + (size_t)(b * NN + q0 + l31) * DDIM + h * HDIM + hi * 4;
#pragma unroll
  for (int rq = 0; rq < 4; ++rq) {
    f32x4 o;
    o[0] = acc0[rq * 4] * inv; o[1] = acc0[rq * 4 + 1] * inv;
    o[2] = acc0[rq * 4 + 2] * inv; o[3] = acc0[rq * 4 + 3] * inv;
    *(f32x4*)(obase + rq * 8) = o;
  }
#pragma unroll
  for (int rq = 0; rq < 4; ++rq) {
    f32x4 o;
    o[0] = acc1[rq * 4] * inv; o[1] = acc1[rq * 4 + 1] * inv;
    o[2] = acc1[rq * 4 + 2] * inv; o[3] = acc1[rq * 4 + 3] * inv;
    *(f32x4*)(obase + 32 + rq * 8) = o;
  }
}

// ---------------- launch ----------------
extern "C" void kernel_launch(void* const* d_in, const int* in_sizes, int n_in,
                              void* d_out, int out_size, void* d_ws, size_t ws_size,
                              hipStream_t stream) {
  const float* x = (const float*)d_in[0];
  const float* W = (const float*)d_in[1];
  const float* bqkv = (const float*)d_in[2];
  float* out = (float*)d_out;
  char* ws = (char*)d_ws;

  // workspace: xb 12.58MB | wt 3.54MB | qb 12.58MB | kp 12.58MB | vp 12.58MB = 53.9MB
  const size_t XB_OFF = 0;
  const size_t WT_OFF = 12582912;
  const size_t QB_OFF = WT_OFF + 3538944;        // 16121856
  const size_t KP_OFF = QB_OFF + 12582912;       // 28704768
  const size_t VP_OFF = KP_OFF + 12582912;       // 41287680
  unsigned short* xb = (unsigned short*)(ws + XB_OFF);
  unsigned short* wt = (unsigned short*)(ws + WT_OFF);
  unsigned short* qbf = (unsigned short*)(ws + QB_OFF);
  unsigned short* kpk = (unsigned short*)(ws + KP_OFF);
  unsigned short* vpk = (unsigned short*)(ws + VP_OFF);

  k_prep<<<dim3(6144 + 1728), dim3(256), 0, stream>>>((const float4*)x, (u16x4*)xb, W, wt);
  k_gemm<<<dim3(1152), dim3(256), 0, stream>>>(xb, wt, bqkv, qbf, kpk, vpk);
  k_attn<<<dim3(768), dim3(256), 0, stream>>>(qbf, kpk, vpk, out);
}

// Round 20
// 82.212 us; speedup vs baseline: 2.6401x; 2.6401x over previous
//
#include <hip/hip_runtime.h>
#include <stdint.h>

// Problem constants
#define BB 8
#define NN 1024
#define DDIM 768
#define HH 12
#define HDIM 64
#define D3 2304   // 3*D
#define MM 8192   // B*N

typedef __attribute__((ext_vector_type(4))) float f32x4;
typedef __attribute__((ext_vector_type(16))) float f32x16;
typedef __attribute__((ext_vector_type(8))) __bf16 bf16x8;
typedef __attribute__((ext_vector_type(8))) unsigned short u16x8;
typedef __attribute__((ext_vector_type(4))) unsigned short u16x4;

__device__ __forceinline__ unsigned short f2bf(float f) {
  unsigned int u = __float_as_uint(f);
  u += 0x7FFFu + ((u >> 16) & 1u);   // RNE
  return (unsigned short)(u >> 16);
}

__device__ __forceinline__ void gload_lds16(const void* g, void* l) {
  __builtin_amdgcn_global_load_lds((const __attribute__((address_space(1))) void*)g,
                                   (__attribute__((address_space(3))) void*)l,
                                   16, 0, 0);
}

__device__ __forceinline__ unsigned cvtpk_bf16(float lo, float hi) {
  unsigned r;
  asm("v_cvt_pk_bf16_f32 %0, %1, %2" : "=v"(r) : "v"(lo), "v"(hi));
  return r;
}

__device__ __forceinline__ bf16x8 mkfrag(unsigned a, unsigned b, unsigned c, unsigned d) {
  union { unsigned u[4]; bf16x8 v; } x;
  x.u[0] = a; x.u[1] = b; x.u[2] = c; x.u[3] = d;
  return x.v;
}

#if __has_builtin(__builtin_amdgcn_exp2f)
#define EXP2(x) __builtin_amdgcn_exp2f(x)
#else
#define EXP2(x) exp2f(x)
#endif

// scale folded into Q at GEMM epilogue: 1/sqrt(64) * log2(e)
#define QSCL 0.18033688f

// ---------------- Kernel 1: merged prep: x fp32->bf16 + W transpose ----------------
__global__ void k_prep(const float4* __restrict__ x, u16x4* __restrict__ xb,
                       const float* __restrict__ W, unsigned short* __restrict__ Wt) {
  __shared__ float tile[32][33];
  const int bid = blockIdx.x;
  if (bid < 6144) {
    int i = bid * 256 + threadIdx.x;
    float4 v = x[i];
    u16x4 o;
    o[0] = f2bf(v.x); o[1] = f2bf(v.y); o[2] = f2bf(v.z); o[3] = f2bf(v.w);
    xb[i] = o;
    return;
  }
  const int bid2 = bid - 6144;
  const int tx = threadIdx.x & 31, ty = threadIdx.x >> 5;
  const int n0 = (bid2 % 72) * 32;
  const int k0 = (bid2 / 72) * 32;
  for (int i = 0; i < 4; ++i) {
    int k = k0 + ty + i * 8;
    tile[ty + i * 8][tx] = W[(size_t)k * D3 + n0 + tx];
  }
  __syncthreads();
  for (int i = 0; i < 4; ++i) {
    int n = n0 + ty + i * 8;
    Wt[(size_t)n * DDIM + k0 + tx] = f2bf(tile[tx][ty + i * 8]);
  }
}

// ---------------- Kernel 2: QKV GEMM (m97 structure) + fused pack epilogue ----------
// 128x128 tile, BK=64, 2-buffer 64KB, XOR-swizzled rows, stage-at-top + vmcnt(8),
// 2 barriers/kt — the R12-proven core (745 TF here) — with m-stripe XCD swizzle.
// Epilogue: nt 0-5 -> compact Q [8192][768]*QSCL; 6-11 -> K pack; 12-17 -> V^T pack.
__global__ __launch_bounds__(256, 2)
void k_gemm(const unsigned short* __restrict__ A, const unsigned short* __restrict__ Bt,
            const float* __restrict__ bias, unsigned short* __restrict__ qb,
            unsigned short* __restrict__ kp, unsigned short* __restrict__ vp) {
  __shared__ char lds[64 * 1024];   // 2 bufs x (A 16KB + B 16KB)
  const int t = threadIdx.x, lane = t & 63, wid = t >> 6;
  // m-stripe XCD swizzle: xcd owns m-tiles [xcd*8, xcd*8+8), n-major inner
  const int orig = blockIdx.x;          // 1152 = 8 xcd * 144
  const int xcd = orig & 7, tt = orig >> 3;
  const int m0 = (xcd * 8 + (tt & 7)) * 128;
  const int n0 = (tt >> 3) * 128;
  const int wr = wid >> 1, wc = wid & 1;
  const int grp = lane >> 4, lc = lane & 15;

  f32x4 acc[4][4];
  for (int i = 0; i < 4; ++i)
    for (int j = 0; j < 4; ++j) acc[i][j] = (f32x4)(0.0f);

  // stage one BK=64 tile pair: A[128][64], B[128][64], XOR-swizzled rows; 8 issues/wave
  auto STAGE = [&](int buf, int kt) {
    char* Ab = lds + buf * 32768;
    char* Bb = Ab + 16384;
#pragma unroll
    for (int i = 0; i < 4; ++i) {
      int id = wid * 4 + i;              // chunk 0..15 (8 rows each)
      int row = id * 8 + (lane >> 3);
      int cs = ((lane & 7) << 4) ^ ((row & 7) << 4);
      gload_lds16((const char*)A + (size_t)(m0 + row) * 1536 + kt * 128 + cs, Ab + id * 1024);
      gload_lds16((const char*)Bt + (size_t)(n0 + row) * 1536 + kt * 128 + cs, Bb + id * 1024);
    }
  };

  STAGE(0, 0);
  for (int kt = 0; kt < 12; ++kt) {
    if (kt < 11) {
      STAGE((kt + 1) & 1, kt + 1);                      // prefetch stays in flight
      asm volatile("s_waitcnt vmcnt(8)" ::: "memory");  // drain only buf(kt)
    } else {
      asm volatile("s_waitcnt vmcnt(0)" ::: "memory");
    }
    __builtin_amdgcn_s_barrier();

    const char* As = lds + (kt & 1) * 32768;
    const char* Bs = As + 16384;
    bf16x8 af[4][2], bfr[4][2];
#pragma unroll
    for (int f = 0; f < 4; ++f)
#pragma unroll
      for (int kk = 0; kk < 2; ++kk) {
        int ra = wr * 64 + f * 16 + lc;
        af[f][kk] = *(const bf16x8*)(As + ra * 128 + ((kk * 64 + grp * 16) ^ ((ra & 7) << 4)));
        int rb = wc * 64 + f * 16 + lc;
        bfr[f][kk] = *(const bf16x8*)(Bs + rb * 128 + ((kk * 64 + grp * 16) ^ ((rb & 7) << 4)));
      }
    __builtin_amdgcn_s_setprio(1);
#pragma unroll
    for (int mf = 0; mf < 4; ++mf)
#pragma unroll
      for (int nf = 0; nf < 4; ++nf) {
        acc[mf][nf] = __builtin_amdgcn_mfma_f32_16x16x32_bf16(af[mf][0], bfr[nf][0], acc[mf][nf], 0, 0, 0);
        acc[mf][nf] = __builtin_amdgcn_mfma_f32_16x16x32_bf16(af[mf][1], bfr[nf][1], acc[mf][nf], 0, 0, 0);
      }
    __builtin_amdgcn_s_setprio(0);
    __builtin_amdgcn_s_barrier();                       // buf(kt) free for restage
  }

  float bv[4];
#pragma unroll
  for (int nf = 0; nf < 4; ++nf) bv[nf] = bias[n0 + wc * 64 + nf * 16 + lc];

  const int nt = n0 >> 7;   // 0..17: Q<6, K<12, else V
  if (nt < 6) {
    // Q: compact [8192][768] bf16, pre-scaled by QSCL
#pragma unroll
    for (int mf = 0; mf < 4; ++mf)
#pragma unroll
      for (int nf = 0; nf < 4; ++nf)
#pragma unroll
        for (int i = 0; i < 4; ++i) {
          int r = m0 + wr * 64 + mf * 16 + grp * 4 + i;
          int c = n0 + wc * 64 + nf * 16 + lc;
          qb[(size_t)r * DDIM + c] = f2bf((acc[mf][nf][i] + bv[nf]) * QSCL);
        }
  } else {
    __syncthreads();   // main-loop LDS reads done in all waves before reuse
    unsigned short* lt = (unsigned short*)lds + wid * 4608;   // 64 x 72 per wave
    const int l31 = lane & 31, hi2 = lane >> 5;
    const int bb = m0 >> 10;
    const int kt_ = ((m0 & 1023) >> 6) + wr;   // 64-token pack tile
    size_t base;
    unsigned short* dst;
    if (nt < 12) {
      // K: LDS [tok][d]
      const int h = ((n0 - DDIM) >> 6) + wc;
      base = ((size_t)(bb * HH + h) * 16 + kt_) * 4096;
      dst = kp;
#pragma unroll
      for (int mf = 0; mf < 4; ++mf)
#pragma unroll
        for (int nf = 0; nf < 4; ++nf)
#pragma unroll
          for (int i = 0; i < 4; ++i)
            lt[(mf * 16 + grp * 4 + i) * 72 + nf * 16 + lc] = f2bf(acc[mf][nf][i] + bv[nf]);
    } else {
      // V: LDS [d][tok]  (transposed)
      const int h = ((n0 - 2 * DDIM) >> 6) + wc;
      base = ((size_t)(bb * HH + h) * 16 + kt_) * 4096;
      dst = vp;
#pragma unroll
      for (int mf = 0; mf < 4; ++mf)
#pragma unroll
        for (int nf = 0; nf < 4; ++nf)
#pragma unroll
          for (int i = 0; i < 4; ++i)
            lt[(nf * 16 + lc) * 72 + mf * 16 + grp * 4 + i] = f2bf(acc[mf][nf][i] + bv[nf]);
    }
    __syncthreads();   // (also orders each wave's own writes before reads)
    // pack store: chunk c2*2+r, lane holds 8 ushorts at row (r*32+l31), col c2*16+hi2*8
#pragma unroll
    for (int c2 = 0; c2 < 4; ++c2)
#pragma unroll
      for (int r = 0; r < 2; ++r)
        *(u16x8*)(dst + base + ((size_t)(c2 * 2 + r) * 64 + lane) * 8) =
          *(const u16x8*)&lt[(r * 32 + l31) * 72 + c2 * 16 + hi2 * 8];
  }
}

// ---------------- Kernel 3: flash attention (fragment-linear LDS, depth-2) ----------
__global__ __launch_bounds__(256, 3)
void k_attn(const unsigned short* __restrict__ qb,
            const unsigned short* __restrict__ kp, const unsigned short* __restrict__ vp,
            float* __restrict__ out) {
  __shared__ char lds[48 * 1024];   // 3 bufs x (K 8KB + V 8KB)
  const int lane = threadIdx.x & 63, wid = threadIdx.x >> 6;
  const int orig = blockIdx.x;
  const int wg = (orig & 7) * 96 + (orig >> 3);
  const int bh = wg >> 3, qt = wg & 7;
  const int b = bh / HH, h = bh % HH;
  const int q0 = qt * 128 + wid * 32;
  const int l31 = lane & 31, hi = lane >> 5;

  auto STAGE = [&](int bi, int kt2) {
    char* buf = lds + bi * 16384;
    const char* gk = (const char*)kp + (size_t)(bh * 16 + kt2) * 8192 + lane * 16;
    const char* gv = (const char*)vp + (size_t)(bh * 16 + kt2) * 8192 + lane * 16;
#pragma unroll
    for (int i = 0; i < 4; ++i) {
      int e = wid * 4 + i;
      const char* g = (e < 8) ? (gk + e * 1024) : (gv + (e - 8) * 1024);
      char* l = (e < 8) ? (buf + e * 1024) : (buf + 8192 + (e - 8) * 1024);
      gload_lds16(g, l);
    }
  };

  // Q B-fragments direct from global FIRST (so later waits don't drain stages)
  bf16x8 qf[4];
  const char* qbase = (const char*)qb + ((size_t)(b * NN + q0 + l31) * DDIM + h * HDIM) * 2;
#pragma unroll
  for (int ds_ = 0; ds_ < 4; ++ds_)
    qf[ds_] = *(const bf16x8*)(qbase + ds_ * 32 + hi * 16);

  STAGE(0, 0);
  STAGE(1, 1);

  f32x16 acc0 = (f32x16)(0.0f), acc1 = (f32x16)(0.0f);
  float l = 0.0f;

  int cur = 0;
  for (int kt = 0; kt < 16; ++kt) {
    if (kt < 15) {
      asm volatile("s_waitcnt vmcnt(4)" ::: "memory");
    } else {
      asm volatile("s_waitcnt vmcnt(0)" ::: "memory");
    }
    __builtin_amdgcn_s_barrier();
    if (kt + 2 < 16) {                 // buf[(kt+2)%3] freed by compute kt-1 (barrier-proven)
      int nx = cur + 2; if (nx >= 3) nx -= 3;
      STAGE(nx, kt + 2);
    }

    const char* Kc = lds + cur * 16384;
    const char* Vc = Kc + 8192;

    bf16x8 kf[4][2];
#pragma unroll
    for (int ds_ = 0; ds_ < 4; ++ds_)
#pragma unroll
      for (int r = 0; r < 2; ++r)
        kf[ds_][r] = *(const bf16x8*)(Kc + (ds_ * 2 + r) * 1024 + lane * 16);

    f32x16 st0 = (f32x16)(0.0f), st1 = (f32x16)(0.0f);
    __builtin_amdgcn_s_setprio(1);
#pragma unroll
    for (int ds_ = 0; ds_ < 4; ++ds_) {
      st0 = __builtin_amdgcn_mfma_f32_32x32x16_bf16(kf[ds_][0], qf[ds_], st0, 0, 0, 0);
      st1 = __builtin_amdgcn_mfma_f32_32x32x16_bf16(kf[ds_][1], qf[ds_], st1, 0, 0, 0);
    }
    __builtin_amdgcn_s_setprio(0);

    bf16x8 vf[4][2];
#pragma unroll
    for (int cc = 0; cc < 4; ++cc)
#pragma unroll
      for (int r = 0; r < 2; ++r)
        vf[cc][r] = *(const bf16x8*)(Vc + (cc * 2 + r) * 1024 + lane * 16);

    float s0 = 0.f, s1 = 0.f, s2 = 0.f, s3 = 0.f;
#pragma unroll
    for (int i = 0; i < 16; i += 4) {
      float p0 = EXP2(st0[i]);
      float p1 = EXP2(st0[i + 1]);
      float p2 = EXP2(st0[i + 2]);
      float p3 = EXP2(st0[i + 3]);
      st0[i] = p0; st0[i + 1] = p1; st0[i + 2] = p2; st0[i + 3] = p3;
      s0 += p0; s1 += p1; s2 += p2; s3 += p3;
    }
#pragma unroll
    for (int i = 0; i < 16; i += 4) {
      float p0 = EXP2(st1[i]);
      float p1 = EXP2(st1[i + 1]);
      float p2 = EXP2(st1[i + 2]);
      float p3 = EXP2(st1[i + 3]);
      st1[i] = p0; st1[i + 1] = p1; st1[i + 2] = p2; st1[i + 3] = p3;
      s0 += p0; s1 += p1; s2 += p2; s3 += p3;
    }
    l += (s0 + s1) + (s2 + s3);

#pragma unroll
    for (int kblk = 0; kblk < 2; ++kblk) {
      const f32x16& sp = kblk ? st1 : st0;
      unsigned c0 = cvtpk_bf16(sp[0], sp[1]),   c1 = cvtpk_bf16(sp[2], sp[3]);
      unsigned c2 = cvtpk_bf16(sp[4], sp[5]),   c3 = cvtpk_bf16(sp[6], sp[7]);
      unsigned c4 = cvtpk_bf16(sp[8], sp[9]),   c5 = cvtpk_bf16(sp[10], sp[11]);
      unsigned c6 = cvtpk_bf16(sp[12], sp[13]), c7 = cvtpk_bf16(sp[14], sp[15]);
      unsigned z0 = hi ? c0 : c2, z1 = hi ? c1 : c3;
      unsigned z2 = hi ? c4 : c6, z3 = hi ? c5 : c7;
      unsigned w0 = __shfl_xor(z0, 32, 64), w1 = __shfl_xor(z1, 32, 64);
      unsigned w2 = __shfl_xor(z2, 32, 64), w3 = __shfl_xor(z3, 32, 64);
      bf16x8 pf0 = mkfrag(hi ? w0 : c0, hi ? w1 : c1, hi ? c2 : w0, hi ? c3 : w1);
      bf16x8 pf1 = mkfrag(hi ? w2 : c4, hi ? w3 : c5, hi ? c6 : w2, hi ? c7 : w3);

      __builtin_amdgcn_s_setprio(1);
#pragma unroll
      for (int ch = 0; ch < 2; ++ch) {
        const int cc = kblk * 2 + ch;
        const bf16x8 pf = ch ? pf1 : pf0;
        acc0 = __builtin_amdgcn_mfma_f32_32x32x16_bf16(vf[cc][0], pf, acc0, 0, 0, 0);
        acc1 = __builtin_amdgcn_mfma_f32_32x32x16_bf16(vf[cc][1], pf, acc1, 0, 0, 0);
      }
      __builtin_amdgcn_s_setprio(0);
    }

    cur = (cur == 2) ? 0 : cur + 1;
  }

  float lf = l + __shfl_xor(l, 32, 64);
  float inv = 1.0f / lf;
  float* obase = out + (size_t)(b * NN + q0 + l31) * DDIM + h * HDIM + hi * 4;
#pragma unroll
  for (int rq = 0; rq < 4; ++rq) {
    f32x4 o;
    o[0] = acc0[rq * 4] * inv; o[1] = acc0[rq * 4 + 1] * inv;
    o[2] = acc0[rq * 4 + 2] * inv; o[3] = acc0[rq * 4 + 3] * inv;
    *(f32x4*)(obase + rq * 8) = o;
  }
#pragma unroll
  for (int rq = 0; rq < 4; ++rq) {
    f32x4 o;
    o[0] = acc1[rq * 4] * inv; o[1] = acc1[rq * 4 + 1] * inv;
    o[2] = acc1[rq * 4 + 2] * inv; o[3] = acc1[rq * 4 + 3] * inv;
    *(f32x4*)(obase + 32 + rq * 8) = o;
  }
}

// ---------------- launch ----------------
extern "C" void kernel_launch(void* const* d_in, const int* in_sizes, int n_in,
                              void* d_out, int out_size, void* d_ws, size_t ws_size,
                              hipStream_t stream) {
  const float* x = (const float*)d_in[0];
  const float* W = (const float*)d_in[1];
  const float* bqkv = (const float*)d_in[2];
  float* out = (float*)d_out;
  char* ws = (char*)d_ws;

  // workspace: xb 12.58MB | wt 3.54MB | qb 12.58MB | kp 12.58MB | vp 12.58MB = 53.9MB
  const size_t XB_OFF = 0;
  const size_t WT_OFF = 12582912;
  const size_t QB_OFF = WT_OFF + 3538944;        // 16121856
  const size_t KP_OFF = QB_OFF + 12582912;       // 28704768
  const size_t VP_OFF = KP_OFF + 12582912;       // 41287680
  unsigned short* xb = (unsigned short*)(ws + XB_OFF);
  unsigned short* wt = (unsigned short*)(ws + WT_OFF);
  unsigned short* qbf = (unsigned short*)(ws + QB_OFF);
  unsigned short* kpk = (unsigned short*)(ws + KP_OFF);
  unsigned short* vpk = (unsigned short*)(ws + VP_OFF);

  k_prep<<<dim3(6144 + 1728), dim3(256), 0, stream>>>((const float4*)x, (u16x4*)xb, W, wt);
  k_gemm<<<dim3(1152), dim3(256), 0, stream>>>(xb, wt, bqkv, qbf, kpk, vpk);
  k_attn<<<dim3(768), dim3(256), 0, stream>>>(qbf, kpk, vpk, out);
}